// Round 5
// baseline (3150.525 us; speedup 1.0000x reference)
//
#include <hip/hip_runtime.h>
#include <cstddef>
#include <cstdint>

#define Hd 51
#define Td 2048
#define NBb 16      // batches per block
#define NTH 512     // 8 waves
#define NBLK 64

typedef _Float16 f16x8 __attribute__((ext_vector_type(8)));
typedef _Float16 f16x4 __attribute__((ext_vector_type(4)));
typedef float    f32x4 __attribute__((ext_vector_type(4)));

// LDS: per buffer, 4 panels indexed (db*2+part): part0 = hi f16, part1 = lo f16.
// Within a panel, CHUNK-TRANSPOSED layout: 16B chunks of the logical k-row are
// strided 256B apart; the 16 batch rows sit at 16B pitch inside each chunk.
// A b128 column read (fixed k-chunk, n varies with lane) then hits bank
// positions 16*(n&7) in lane order == the consecutive conflict-free pattern.
//  buf0: logical row 128 B ( 8 chunks), k: [h0 0..50][pad][x 52,53][one 54][pad]
//  buf1: logical row 256 B (16 chunks), k: [h0 0..50][pad][h1 56..106][pad][one 112][pad]
//  buf2: logical row 256 B (16 chunks), k: [h1 0..50][pad][h2 56..106][pad][one 112][pad]
#define RB0   128
#define RB12  256
#define BASE0 0
#define BASE1 8192
#define BASE2 24576
#define LDSB  40960

__device__ __forceinline__ int vaddr(int base, int rowB, int db, int part, int n, int off) {
    // panel stride = 16 rows * rowB (unchanged); chunk-transposed inside panel
    return base + (db * 2 + part) * (16 * rowB) + ((off >> 4) << 8) + (n << 4) + (off & 15);
}

__device__ __forceinline__ float fast_rcp(float x) { return __builtin_amdgcn_rcpf(x); }
__device__ __forceinline__ float sigm(float x) { return fast_rcp(1.f + __expf(-x)); }
__device__ __forceinline__ float tanh_g(float x) { return fmaf(2.f, fast_rcp(1.f + __expf(-2.f * x)), -1.f); }
__device__ __forceinline__ float tanh_c(float x) {
    float e = __expf(-2.f * fabsf(x));
    float t = (1.f - e) * fast_rcp(1.f + e);
    return copysignf(t, x);
}

// i,f,g,o -> c,h update; writes h as hi+lo f16 pair into 1 or 2 buffers.
// lo panel of a buffer sits +16*rowB bytes after the hi panel.
__device__ __forceinline__ void update_write(unsigned char* lds, const f32x4* acc,
                                             float (&cs)[4], int aH1, int rB1,
                                             int aH2, int rB2) {
    f16x4 hH, hL;
    #pragma unroll
    for (int r = 0; r < 4; ++r) {
        float gi = sigm(acc[0][r]);
        float gf = sigm(acc[1][r]);
        float gg = tanh_g(acc[2][r]);
        float go = sigm(acc[3][r]);
        float cn = fmaf(gf, cs[r], gi * gg);
        cs[r] = cn;
        float h  = go * tanh_c(cn);
        _Float16 hi = (_Float16)h;
        hH[r] = hi;
        hL[r] = (_Float16)(h - (float)hi);
    }
    *(f16x4*)(lds + aH1) = hH;
    *(f16x4*)(lds + aH1 + NBb * rB1) = hL;
    if (aH2 >= 0) {
        *(f16x4*)(lds + aH2) = hH;
        *(f16x4*)(lds + aH2 + NBb * rB2) = hL;
    }
}

__global__ __launch_bounds__(NTH, 2)
void lstm3_mfma(const float* __restrict__ g_input, const float* __restrict__ g_time,
                const float* __restrict__ Wih0, const float* __restrict__ Whh0,
                const float* __restrict__ bih0, const float* __restrict__ bhh0,
                const float* __restrict__ Wih1, const float* __restrict__ Whh1,
                const float* __restrict__ bih1, const float* __restrict__ bhh1,
                const float* __restrict__ Wih2, const float* __restrict__ Whh2,
                const float* __restrict__ bih2, const float* __restrict__ bhh2,
                const float* __restrict__ Wlin, const float* __restrict__ blin,
                float* __restrict__ g_out)
{
    __shared__ __align__(16) unsigned char lds[LDSB];

    const int tid  = threadIdx.x;
    const int lane = tid & 63;
    const int w    = tid >> 6;       // wave 0..7
    const int c    = w & 3;          // element-chunk (16 elements)
    const bool low = (w < 4);        // low waves: L0+L1 ; high waves: L2+head
    const int ncol = lane & 15;      // batch col (B) / A-row-in-tile
    const int kg   = lane >> 4;      // k-group 0..3
    const int b0   = blockIdx.x * NBb;

    // ---- zero LDS ----
    for (int i = tid * 4; i < LDSB; i += NTH * 4) *(uint32_t*)(lds + i) = 0u;
    __syncthreads();

    // one-slots (bias column of B, hi panels only) in BOTH double buffers; x(t=0)
    if (tid < 32) {
        int db = tid >> 4, n = tid & 15;
        *(unsigned short*)(lds + vaddr(BASE0, RB0,  db, 0, n,  54 * 2)) = 0x3C00; // f16 1.0
        *(unsigned short*)(lds + vaddr(BASE1, RB12, db, 0, n, 112 * 2)) = 0x3C00;
        *(unsigned short*)(lds + vaddr(BASE2, RB12, db, 0, n, 112 * 2)) = 0x3C00;
    } else if (tid >= 64 && tid < 96) {
        int i = tid - 64; int n = i & 15, f = i >> 4;
        const float* src = f ? g_time : g_input;
        float v = src[(size_t)(b0 + n) * Td];
        _Float16 hi = (_Float16)v;
        *(_Float16*)(lds + vaddr(BASE0, RB0, 0, 0, n, (52 + f) * 2)) = hi;
        *(_Float16*)(lds + vaddr(BASE0, RB0, 0, 1, n, (52 + f) * 2)) = (_Float16)(v - (float)hi);
    }

    // ---- load weight A-fragments (f16 hi only) ----
    // A-frag lane map (16x16x32): row = 16*tile + (lane&15), k = 32*s + 8*(lane>>4) + e
    // wave owns tiles {c, c+4, c+8, c+12}: gate gs rows = 64*gs + er, er = 16c + ncol
    const int er = 16 * c + ncol;
    const bool rvalid = (er < Hd);
    f16x8 AF[24];   // low: [0..7]=L0 (4 gates x 2 ksteps), [8..23]=L1 ; high: [0..15]=L2

    if (low) {
        #pragma unroll
        for (int gs = 0; gs < 4; ++gs) {
            const int sr = gs * Hd + er;
            #pragma unroll
            for (int s = 0; s < 2; ++s)
                #pragma unroll
                for (int e = 0; e < 8; ++e) {
                    const int kk = 32 * s + 8 * kg + e;
                    float v = 0.f;
                    if (rvalid) {
                        if (kk < 51)                   v = Whh0[sr * 51 + kk];
                        else if (kk == 52 || kk == 53) v = Wih0[sr * 2 + (kk - 52)];
                        else if (kk == 54)             v = bih0[sr] + bhh0[sr];
                    }
                    AF[gs * 2 + s][e] = (_Float16)v;
                }
            #pragma unroll
            for (int s = 0; s < 4; ++s)
                #pragma unroll
                for (int e = 0; e < 8; ++e) {
                    const int kk = 32 * s + 8 * kg + e;
                    float v = 0.f;
                    if (rvalid) {
                        if (kk < 51)                   v = Wih1[sr * 51 + kk];
                        else if (kk >= 56 && kk < 107) v = Whh1[sr * 51 + (kk - 56)];
                        else if (kk == 112)            v = bih1[sr] + bhh1[sr];
                    }
                    AF[8 + gs * 4 + s][e] = (_Float16)v;
                }
        }
    } else {
        #pragma unroll
        for (int gs = 0; gs < 4; ++gs) {
            const int sr = gs * Hd + er;
            #pragma unroll
            for (int s = 0; s < 4; ++s)
                #pragma unroll
                for (int e = 0; e < 8; ++e) {
                    const int kk = 32 * s + 8 * kg + e;
                    float v = 0.f;
                    if (rvalid) {
                        if (kk < 51)                   v = Wih2[sr * 51 + kk];
                        else if (kk >= 56 && kk < 107) v = Whh2[sr * 51 + (kk - 56)];
                        else if (kk == 112)            v = bih2[sr] + bhh2[sr];
                    } else if (gs == 0 && (er == 52 || er == 53)) {
                        const int hr = er - 52;        // head rows: W_lin embedded
                        if (kk >= 56 && kk < 107)      v = Wlin[hr * 51 + (kk - 56)];
                        else if (kk == 112)            v = blin[hr];
                    }
                    AF[gs * 4 + s][e] = (_Float16)v;
                }
        }
    }

    float cs[8];
    #pragma unroll
    for (int i = 0; i < 8; ++i) cs[i] = 0.f;
    float (&cs_a)[4] = *(float(*)[4])&cs[0];
    float (&cs_b)[4] = *(float(*)[4])&cs[4];

    const int e0 = 16 * c + 4 * kg;   // first element of this lane's 4 C rows
    const bool wr_ok = (e0 < Hd);     // guard: never touch x/one/pad slots
    const f32x4 Z = {0.f, 0.f, 0.f, 0.f};

    __syncthreads();

    // layer skew: iter n computes L0@t=n, L1@t=n-1, L2@t=n-2, head@t=n-3
    for (int n = 0; n <= Td + 2; ++n) {
        const int rb = n & 1, wb = rb ^ 1;

        if (low) {
            const bool doL0 = (n < Td);
            const bool doL1 = (n >= 1 && n <= Td);

            // ---- issue ALL ds_reads up front (L1 reads must not serialize
            //      behind L0's LDS writes; buffers rb vs wb never alias) ----
            f16x8 B0h, B1h, B0l, B1l;      // L0
            f16x8 Bh[4], Bl[4];            // L1
            if (doL0) {
                B0h = *(const f16x8*)(lds + vaddr(BASE0, RB0, rb, 0, ncol, 16 * kg));
                B1h = *(const f16x8*)(lds + vaddr(BASE0, RB0, rb, 0, ncol, 64 + 16 * kg));
                B0l = *(const f16x8*)(lds + vaddr(BASE0, RB0, rb, 1, ncol, 16 * kg));
                B1l = *(const f16x8*)(lds + vaddr(BASE0, RB0, rb, 1, ncol, 64 + 16 * kg));
            }
            if (doL1) {
                #pragma unroll
                for (int s = 0; s < 4; ++s) {
                    Bh[s] = *(const f16x8*)(lds + vaddr(BASE1, RB12, rb, 0, ncol, 64 * s + 16 * kg));
                    Bl[s] = *(const f16x8*)(lds + vaddr(BASE1, RB12, rb, 1, ncol, 64 * s + 16 * kg));
                }
            }

            if (doL0) {  // ---- L0 ----
                f32x4 acc[4] = {Z, Z, Z, Z};
                #pragma unroll
                for (int gs = 0; gs < 4; ++gs) {
                    acc[gs] = __builtin_amdgcn_mfma_f32_16x16x32_f16(AF[gs * 2 + 0], B0h, acc[gs], 0, 0, 0);
                    acc[gs] = __builtin_amdgcn_mfma_f32_16x16x32_f16(AF[gs * 2 + 0], B0l, acc[gs], 0, 0, 0);
                    acc[gs] = __builtin_amdgcn_mfma_f32_16x16x32_f16(AF[gs * 2 + 1], B1h, acc[gs], 0, 0, 0);
                    acc[gs] = __builtin_amdgcn_mfma_f32_16x16x32_f16(AF[gs * 2 + 1], B1l, acc[gs], 0, 0, 0);
                }
                if (wr_ok)
                    update_write(lds, acc, cs_a,
                                 vaddr(BASE0, RB0,  wb, 0, ncol, 2 * e0), RB0,
                                 vaddr(BASE1, RB12, wb, 0, ncol, 2 * e0), RB12);
            }
            if (doL1) {  // ---- L1 ----
                f32x4 acc[4] = {Z, Z, Z, Z};
                #pragma unroll
                for (int s = 0; s < 4; ++s)
                    #pragma unroll
                    for (int gs = 0; gs < 4; ++gs) {
                        acc[gs] = __builtin_amdgcn_mfma_f32_16x16x32_f16(AF[8 + gs * 4 + s], Bh[s], acc[gs], 0, 0, 0);
                        acc[gs] = __builtin_amdgcn_mfma_f32_16x16x32_f16(AF[8 + gs * 4 + s], Bl[s], acc[gs], 0, 0, 0);
                    }
                if (wr_ok)
                    update_write(lds, acc, cs_b,
                                 vaddr(BASE1, RB12, wb, 0, ncol, 112 + 2 * e0), RB12,
                                 vaddr(BASE2, RB12, wb, 0, ncol, 2 * e0), RB12);
            }
        } else {
            const bool doL2 = (n >= 2);
            const bool dopf = (w == 4 && lane < 32 && (n + 1) < Td);

            // issue x global load early (latency hides under L2 compute)
            float pfv = 0.f;
            int nb = lane & 15, f = (lane >> 4) & 1;
            if (dopf) {
                const float* src = f ? g_time : g_input;
                pfv = src[(size_t)(b0 + nb) * Td + (n + 1)];
            }

            f16x8 Bh[4], Bl[4];
            if (doL2) {
                #pragma unroll
                for (int s = 0; s < 4; ++s) {
                    Bh[s] = *(const f16x8*)(lds + vaddr(BASE2, RB12, rb, 0, ncol, 64 * s + 16 * kg));
                    Bl[s] = *(const f16x8*)(lds + vaddr(BASE2, RB12, rb, 1, ncol, 64 * s + 16 * kg));
                }
                f32x4 acc[4] = {Z, Z, Z, Z};
                #pragma unroll
                for (int s = 0; s < 4; ++s)
                    #pragma unroll
                    for (int gs = 0; gs < 4; ++gs) {
                        acc[gs] = __builtin_amdgcn_mfma_f32_16x16x32_f16(AF[gs * 4 + s], Bh[s], acc[gs], 0, 0, 0);
                        acc[gs] = __builtin_amdgcn_mfma_f32_16x16x32_f16(AF[gs * 4 + s], Bl[s], acc[gs], 0, 0, 0);
                    }
                if (n <= Td + 1 && wr_ok)
                    update_write(lds, acc, cs_a,
                                 vaddr(BASE2, RB12, wb, 0, ncol, 112 + 2 * e0), RB12,
                                 -1, 0);
                if (w == 7 && kg == 1 && n >= 3) {
                    // head rows 52,53 -> tile c=3, C rows 4,5 -> kg=1, regs 0,1
                    float mean = acc[0][0];
                    float spre = acc[0][1];
                    float sp = (spre > 30.f) ? spre : __logf(1.f + __expf(spre));
                    const int t = n - 3;
                    float2 o2 = make_float2(mean, sp);
                    *(float2*)&g_out[((size_t)(b0 + ncol) * Td + t) * 2] = o2;
                }
            }
            if (dopf) {  // x for L0@t=n+1 into wb buffer
                _Float16 hi = (_Float16)pfv;
                *(_Float16*)(lds + vaddr(BASE0, RB0, wb, 0, nb, (52 + f) * 2)) = hi;
                *(_Float16*)(lds + vaddr(BASE0, RB0, wb, 1, nb, (52 + f) * 2)) = (_Float16)(pfv - (float)hi);
            }
        }
        __syncthreads();  // single barrier: wb writes become next iter's rb reads
    }
}

extern "C" void kernel_launch(void* const* d_in, const int* in_sizes, int n_in,
                              void* d_out, int out_size, void* d_ws, size_t ws_size,
                              hipStream_t stream) {
    const float* input = (const float*)d_in[0];
    const float* timei = (const float*)d_in[1];
    const float* Wih0  = (const float*)d_in[2];
    const float* Whh0  = (const float*)d_in[3];
    const float* bih0  = (const float*)d_in[4];
    const float* bhh0  = (const float*)d_in[5];
    const float* Wih1  = (const float*)d_in[6];
    const float* Whh1  = (const float*)d_in[7];
    const float* bih1  = (const float*)d_in[8];
    const float* bhh1  = (const float*)d_in[9];
    const float* Wih2  = (const float*)d_in[10];
    const float* Whh2  = (const float*)d_in[11];
    const float* bih2  = (const float*)d_in[12];
    const float* bhh2  = (const float*)d_in[13];
    const float* Wlin  = (const float*)d_in[14];
    const float* blin  = (const float*)d_in[15];
    float* out = (float*)d_out;

    lstm3_mfma<<<dim3(NBLK), dim3(NTH), 0, stream>>>(
        input, timei,
        Wih0, Whh0, bih0, bhh0,
        Wih1, Whh1, bih1, bhh1,
        Wih2, Whh2, bih2, bhh2,
        Wlin, blin, out);
}

// Round 6
// 2281.877 us; speedup vs baseline: 1.3807x; 1.3807x over previous
//
#include <hip/hip_runtime.h>
#include <cstddef>
#include <cstdint>

#define Hd 51
#define Td 2048
#define NBb 16      // batches per block
#define NTH 512     // 8 waves
#define NBLK 64

typedef _Float16 f16x8 __attribute__((ext_vector_type(8)));
typedef _Float16 f16x4 __attribute__((ext_vector_type(4)));
typedef float    f32x4 __attribute__((ext_vector_type(4)));

// LDS: per buffer, 2 panels (double buffer db). Within a panel, CHUNK-
// TRANSPOSED layout: 16B chunks of the logical k-row are strided 256B apart;
// the 16 batch rows sit at 16B pitch inside each chunk -> b128 column reads
// (fixed chunk, n varies with lane) are conflict-free.
//  buf0: logical row 128 B ( 8 chunks), k: [h0 0..50][pad][x 52,53][one 54][pad]
//  buf1: logical row 256 B (16 chunks), k: [h0 0..50][pad][h1 56..106][pad][one 112][pad]
//  buf2: logical row 256 B (16 chunks), k: [h1 0..50][pad][h2 56..106][pad][one 112][pad]
#define RB0   128
#define RB12  256
#define BASE0 0
#define BASE1 4096
#define BASE2 12288
#define LDSB  20480

#define LOG2E  1.44269504f
#define LOG2E2 2.88539008f

__device__ __forceinline__ int vaddr(int base, int rowB, int db, int n, int off) {
    return base + db * (16 * rowB) + ((off >> 4) << 8) + (n << 4) + (off & 15);
}

__device__ __forceinline__ float fast_rcp(float x) { return __builtin_amdgcn_rcpf(x); }
__device__ __forceinline__ float exp2_fast(float x) {
#if __has_builtin(__builtin_amdgcn_exp2f)
    return __builtin_amdgcn_exp2f(x);
#else
    return exp2f(x);
#endif
}

// preactivations arrive PRE-SCALED: a' = a*log2e (i,f,o) or a*2*log2e (g)
__device__ __forceinline__ float sigm2(float ap)  { return fast_rcp(1.f + exp2_fast(-ap)); }
__device__ __forceinline__ float tanh2(float ap)  { return fmaf(2.f, fast_rcp(1.f + exp2_fast(-ap)), -1.f); }
__device__ __forceinline__ float tanh_c(float x) {   // x in true units
    float e = exp2_fast(-LOG2E2 * fabsf(x));
    float t = (1.f - e) * fast_rcp(1.f + e);
    return copysignf(t, x);
}

// i,f,g,o -> c,h update; writes h (f16) into 1 or 2 buffers.
__device__ __forceinline__ void update_write(unsigned char* lds, const f32x4* acc,
                                             float (&cs)[4], int aH1, int aH2) {
    f16x4 hv;
    #pragma unroll
    for (int r = 0; r < 4; ++r) {
        float gi = sigm2(acc[0][r]);
        float gf = sigm2(acc[1][r]);
        float gg = tanh2(acc[2][r]);
        float go = sigm2(acc[3][r]);
        float cn = fmaf(gf, cs[r], gi * gg);
        cs[r] = cn;
        hv[r] = (_Float16)(go * tanh_c(cn));
    }
    *(f16x4*)(lds + aH1) = hv;
    if (aH2 >= 0) *(f16x4*)(lds + aH2) = hv;
}

__global__ __launch_bounds__(NTH, 2)
void lstm3_mfma(const float* __restrict__ g_input, const float* __restrict__ g_time,
                const float* __restrict__ Wih0, const float* __restrict__ Whh0,
                const float* __restrict__ bih0, const float* __restrict__ bhh0,
                const float* __restrict__ Wih1, const float* __restrict__ Whh1,
                const float* __restrict__ bih1, const float* __restrict__ bhh1,
                const float* __restrict__ Wih2, const float* __restrict__ Whh2,
                const float* __restrict__ bih2, const float* __restrict__ bhh2,
                const float* __restrict__ Wlin, const float* __restrict__ blin,
                float* __restrict__ g_out)
{
    __shared__ __align__(16) unsigned char lds[LDSB];

    const int tid  = threadIdx.x;
    const int lane = tid & 63;
    const int w    = tid >> 6;       // wave 0..7
    const int c    = w & 3;          // element-chunk (16 elements)
    const bool low = (w < 4);        // low waves: L0+L1 ; high waves: L2+head
    const int ncol = lane & 15;      // batch col (B) / A-row-in-tile
    const int kg   = lane >> 4;      // k-group 0..3
    const int b0   = blockIdx.x * NBb;

    // ---- zero LDS ----
    for (int i = tid * 4; i < LDSB; i += NTH * 4) *(uint32_t*)(lds + i) = 0u;
    __syncthreads();

    // one-slots (bias column of B) in BOTH double buffers; x(t=0)
    if (tid < 32) {
        int db = tid >> 4, n = tid & 15;
        *(unsigned short*)(lds + vaddr(BASE0, RB0,  db, n,  54 * 2)) = 0x3C00; // f16 1.0
        *(unsigned short*)(lds + vaddr(BASE1, RB12, db, n, 112 * 2)) = 0x3C00;
        *(unsigned short*)(lds + vaddr(BASE2, RB12, db, n, 112 * 2)) = 0x3C00;
    } else if (tid >= 64 && tid < 96) {
        int i = tid - 64; int n = i & 15, f = i >> 4;
        const float* src = f ? g_time : g_input;
        float v = src[(size_t)(b0 + n) * Td];
        *(_Float16*)(lds + vaddr(BASE0, RB0, 0, n, (52 + f) * 2)) = (_Float16)v;
    }

    // ---- load weight A-fragments (f16, log2e-prescaled) ----
    // A-frag lane map (16x16x32): row = 16*tile + (lane&15), k = 32*s + 8*(lane>>4) + e
    // wave owns tiles {c, c+4, c+8, c+12}: gate gs rows = 64*gs + er, er = 16c + ncol
    const int er = 16 * c + ncol;
    const bool rvalid = (er < Hd);
    f16x8 AF[24];   // low: [0..7]=L0 (4 gates x 2 ksteps), [8..23]=L1 ; high: [0..15]=L2

    if (low) {
        #pragma unroll
        for (int gs = 0; gs < 4; ++gs) {
            const int sr = gs * Hd + er;
            const float S = (gs == 2) ? LOG2E2 : LOG2E;   // g-gate: tanh(a)=2sig(2a)-1
            #pragma unroll
            for (int s = 0; s < 2; ++s)
                #pragma unroll
                for (int e = 0; e < 8; ++e) {
                    const int kk = 32 * s + 8 * kg + e;
                    float v = 0.f;
                    if (rvalid) {
                        if (kk < 51)                   v = Whh0[sr * 51 + kk];
                        else if (kk == 52 || kk == 53) v = Wih0[sr * 2 + (kk - 52)];
                        else if (kk == 54)             v = bih0[sr] + bhh0[sr];
                    }
                    AF[gs * 2 + s][e] = (_Float16)(v * S);
                }
            #pragma unroll
            for (int s = 0; s < 4; ++s)
                #pragma unroll
                for (int e = 0; e < 8; ++e) {
                    const int kk = 32 * s + 8 * kg + e;
                    float v = 0.f;
                    if (rvalid) {
                        if (kk < 51)                   v = Wih1[sr * 51 + kk];
                        else if (kk >= 56 && kk < 107) v = Whh1[sr * 51 + (kk - 56)];
                        else if (kk == 112)            v = bih1[sr] + bhh1[sr];
                    }
                    AF[8 + gs * 4 + s][e] = (_Float16)(v * S);
                }
        }
    } else {
        #pragma unroll
        for (int gs = 0; gs < 4; ++gs) {
            const int sr = gs * Hd + er;
            const float S = (gs == 2) ? LOG2E2 : LOG2E;
            #pragma unroll
            for (int s = 0; s < 4; ++s)
                #pragma unroll
                for (int e = 0; e < 8; ++e) {
                    const int kk = 32 * s + 8 * kg + e;
                    float v = 0.f;
                    float sc = S;
                    if (rvalid) {
                        if (kk < 51)                   v = Wih2[sr * 51 + kk];
                        else if (kk >= 56 && kk < 107) v = Whh2[sr * 51 + (kk - 56)];
                        else if (kk == 112)            v = bih2[sr] + bhh2[sr];
                    } else if (gs == 0 && (er == 52 || er == 53)) {
                        const int hr = er - 52;        // head rows: LINEAR, unscaled
                        sc = 1.f;
                        if (kk >= 56 && kk < 107)      v = Wlin[hr * 51 + (kk - 56)];
                        else if (kk == 112)            v = blin[hr];
                    }
                    AF[gs * 4 + s][e] = (_Float16)(v * sc);
                }
        }
    }

    float cs[8];
    #pragma unroll
    for (int i = 0; i < 8; ++i) cs[i] = 0.f;
    float (&cs_a)[4] = *(float(*)[4])&cs[0];
    float (&cs_b)[4] = *(float(*)[4])&cs[4];

    const int e0 = 16 * c + 4 * kg;   // first element of this lane's 4 C rows
    const bool wr_ok = (e0 < Hd);     // guard: never touch x/one slots
    const f32x4 Z = {0.f, 0.f, 0.f, 0.f};

    __syncthreads();

    // layer skew: iter n computes L0@t=n, L1@t=n-1, L2@t=n-2, head@t=n-3
    for (int n = 0; n <= Td + 2; ++n) {
        const int rb = n & 1, wb = rb ^ 1;

        if (low) {
            const bool doL0 = (n < Td);
            const bool doL1 = (n >= 1 && n <= Td);

            // issue ALL ds_reads up front (L1 reads must not serialize behind
            // L0's LDS writes; rb vs wb buffers never alias)
            f16x8 B0, B1;       // L0
            f16x8 Bh[4];        // L1
            if (doL0) {
                B0 = *(const f16x8*)(lds + vaddr(BASE0, RB0, rb, ncol, 16 * kg));
                B1 = *(const f16x8*)(lds + vaddr(BASE0, RB0, rb, ncol, 64 + 16 * kg));
            }
            if (doL1) {
                #pragma unroll
                for (int s = 0; s < 4; ++s)
                    Bh[s] = *(const f16x8*)(lds + vaddr(BASE1, RB12, rb, ncol, 64 * s + 16 * kg));
            }

            if (doL0) {  // ---- L0 ----
                f32x4 acc[4] = {Z, Z, Z, Z};
                #pragma unroll
                for (int gs = 0; gs < 4; ++gs) {
                    acc[gs] = __builtin_amdgcn_mfma_f32_16x16x32_f16(AF[gs * 2 + 0], B0, acc[gs], 0, 0, 0);
                    acc[gs] = __builtin_amdgcn_mfma_f32_16x16x32_f16(AF[gs * 2 + 1], B1, acc[gs], 0, 0, 0);
                }
                if (wr_ok)
                    update_write(lds, acc, cs_a,
                                 vaddr(BASE0, RB0,  wb, ncol, 2 * e0),
                                 vaddr(BASE1, RB12, wb, ncol, 2 * e0));
            }
            if (doL1) {  // ---- L1 ----
                f32x4 acc[4] = {Z, Z, Z, Z};
                #pragma unroll
                for (int s = 0; s < 4; ++s)
                    #pragma unroll
                    for (int gs = 0; gs < 4; ++gs)
                        acc[gs] = __builtin_amdgcn_mfma_f32_16x16x32_f16(AF[8 + gs * 4 + s], Bh[s], acc[gs], 0, 0, 0);
                if (wr_ok)
                    update_write(lds, acc, cs_b,
                                 vaddr(BASE1, RB12, wb, ncol, 112 + 2 * e0),
                                 vaddr(BASE2, RB12, wb, ncol, 2 * e0));
            }
        } else {
            const bool doL2 = (n >= 2);
            const bool dopf = (w == 4 && lane < 32 && (n + 1) < Td);

            // issue x global load early (latency hides under L2 compute)
            float pfv = 0.f;
            int nb = lane & 15, f = (lane >> 4) & 1;
            if (dopf) {
                const float* src = f ? g_time : g_input;
                pfv = src[(size_t)(b0 + nb) * Td + (n + 1)];
            }

            if (doL2) {  // ---- L2 (+head rows 52,53 inside gs=0 tiles) ----
                f16x8 Bh[4];
                #pragma unroll
                for (int s = 0; s < 4; ++s)
                    Bh[s] = *(const f16x8*)(lds + vaddr(BASE2, RB12, rb, ncol, 64 * s + 16 * kg));
                f32x4 acc[4] = {Z, Z, Z, Z};
                #pragma unroll
                for (int s = 0; s < 4; ++s)
                    #pragma unroll
                    for (int gs = 0; gs < 4; ++gs)
                        acc[gs] = __builtin_amdgcn_mfma_f32_16x16x32_f16(AF[gs * 4 + s], Bh[s], acc[gs], 0, 0, 0);
                if (n <= Td + 1 && wr_ok)
                    update_write(lds, acc, cs_a,
                                 vaddr(BASE2, RB12, wb, ncol, 112 + 2 * e0), -1);
                if (w == 7 && kg == 1 && n >= 3) {
                    // head rows 52,53 -> tile c=3, C rows 4,5 -> kg=1, regs 0,1
                    float mean = acc[0][0];
                    float spre = acc[0][1];
                    float sp = (spre > 30.f) ? spre : __logf(1.f + __expf(spre));
                    const int t = n - 3;
                    float2 o2 = make_float2(mean, sp);
                    *(float2*)&g_out[((size_t)(b0 + ncol) * Td + t) * 2] = o2;
                }
            }
            if (dopf) {  // x for L0@t=n+1 into wb buffer
                *(_Float16*)(lds + vaddr(BASE0, RB0, wb, nb, (52 + f) * 2)) = (_Float16)pfv;
            }
        }
        __syncthreads();  // single barrier: wb writes become next iter's rb reads
    }
}

extern "C" void kernel_launch(void* const* d_in, const int* in_sizes, int n_in,
                              void* d_out, int out_size, void* d_ws, size_t ws_size,
                              hipStream_t stream) {
    const float* input = (const float*)d_in[0];
    const float* timei = (const float*)d_in[1];
    const float* Wih0  = (const float*)d_in[2];
    const float* Whh0  = (const float*)d_in[3];
    const float* bih0  = (const float*)d_in[4];
    const float* bhh0  = (const float*)d_in[5];
    const float* Wih1  = (const float*)d_in[6];
    const float* Whh1  = (const float*)d_in[7];
    const float* bih1  = (const float*)d_in[8];
    const float* bhh1  = (const float*)d_in[9];
    const float* Wih2  = (const float*)d_in[10];
    const float* Whh2  = (const float*)d_in[11];
    const float* bih2  = (const float*)d_in[12];
    const float* bhh2  = (const float*)d_in[13];
    const float* Wlin  = (const float*)d_in[14];
    const float* blin  = (const float*)d_in[15];
    float* out = (float*)d_out;

    lstm3_mfma<<<dim3(NBLK), dim3(NTH), 0, stream>>>(
        input, timei,
        Wih0, Whh0, bih0, bhh0,
        Wih1, Whh1, bih1, bhh1,
        Wih2, Whh2, bih2, bhh2,
        Wlin, blin, out);
}

// Round 7
// 2098.719 us; speedup vs baseline: 1.5012x; 1.0873x over previous
//
#include <hip/hip_runtime.h>
#include <cstddef>
#include <cstdint>

#define Hd 51
#define Td 2048
#define NBb 16      // batches per block
#define NTH 768     // 12 waves: 4×L0, 4×L1, 4×L2 (one of each per SIMD)
#define NBLK 64

typedef _Float16 f16x8 __attribute__((ext_vector_type(8)));
typedef _Float16 f16x4 __attribute__((ext_vector_type(4)));
typedef float    f32x4 __attribute__((ext_vector_type(4)));

// LDS: per buffer, 2 panels (double buffer db). Within a panel, CHUNK-
// TRANSPOSED layout: 16B chunks of the logical k-row are strided 256B apart;
// the 16 batch rows sit at 16B pitch inside each chunk -> b128 column reads
// (fixed chunk, n varies with lane) are conflict-free.
//  buf0: logical row 128 B ( 8 chunks), k: [h0 0..50][pad][x 52,53][one 54][pad]
//  buf1: logical row 256 B (16 chunks), k: [h0 0..50][pad][h1 56..106][pad][one 112][pad]
//  buf2: logical row 256 B (16 chunks), k: [h1 0..50][pad][h2 56..106][pad][one 112][pad]
#define RB0   128
#define RB12  256
#define BASE0 0
#define BASE1 4096
#define BASE2 12288
#define LDSB  20480

#define LOG2E  1.44269504f
#define LOG2E2 2.88539008f

__device__ __forceinline__ int vaddr(int base, int rowB, int db, int n, int off) {
    return base + db * (16 * rowB) + ((off >> 4) << 8) + (n << 4) + (off & 15);
}

__device__ __forceinline__ float fast_rcp(float x) { return __builtin_amdgcn_rcpf(x); }
__device__ __forceinline__ float exp2_fast(float x) {
#if __has_builtin(__builtin_amdgcn_exp2f)
    return __builtin_amdgcn_exp2f(x);
#else
    return exp2f(x);
#endif
}

// preactivations arrive PRE-SCALED: a' = a*log2e (i,f,o) or a*2*log2e (g)
__device__ __forceinline__ float sigm2(float ap)  { return fast_rcp(1.f + exp2_fast(-ap)); }
__device__ __forceinline__ float tanh2(float ap)  { return fmaf(2.f, fast_rcp(1.f + exp2_fast(-ap)), -1.f); }
__device__ __forceinline__ float tanh_c(float x) {   // x in true units
    float e = exp2_fast(-LOG2E2 * fabsf(x));
    float t = (1.f - e) * fast_rcp(1.f + e);
    return copysignf(t, x);
}

// i,f,g,o -> c,h update; writes h (f16) into 1 or 2 buffers.
__device__ __forceinline__ void update_write(unsigned char* lds, const f32x4* acc,
                                             float (&cs)[4], int aH1, int aH2) {
    f16x4 hv;
    #pragma unroll
    for (int r = 0; r < 4; ++r) {
        float gi = sigm2(acc[0][r]);
        float gf = sigm2(acc[1][r]);
        float gg = tanh2(acc[2][r]);
        float go = sigm2(acc[3][r]);
        float cn = fmaf(gf, cs[r], gi * gg);
        cs[r] = cn;
        hv[r] = (_Float16)(go * tanh_c(cn));
    }
    *(f16x4*)(lds + aH1) = hv;
    if (aH2 >= 0) *(f16x4*)(lds + aH2) = hv;
}

__global__ __launch_bounds__(NTH, 3)
void lstm3_mfma(const float* __restrict__ g_input, const float* __restrict__ g_time,
                const float* __restrict__ Wih0, const float* __restrict__ Whh0,
                const float* __restrict__ bih0, const float* __restrict__ bhh0,
                const float* __restrict__ Wih1, const float* __restrict__ Whh1,
                const float* __restrict__ bih1, const float* __restrict__ bhh1,
                const float* __restrict__ Wih2, const float* __restrict__ Whh2,
                const float* __restrict__ bih2, const float* __restrict__ bhh2,
                const float* __restrict__ Wlin, const float* __restrict__ blin,
                float* __restrict__ g_out)
{
    __shared__ __align__(16) unsigned char lds[LDSB];

    const int tid  = threadIdx.x;
    const int lane = tid & 63;
    const int w    = tid >> 6;       // wave 0..11
    const int g    = w >> 2;         // layer group: 0=L0, 1=L1, 2=L2
    const int c    = w & 3;          // element-chunk (16 gate-elements / tile set)
    const int ncol = lane & 15;      // batch col (B) / A-row-in-tile
    const int kg   = lane >> 4;      // k-group 0..3
    const int b0   = blockIdx.x * NBb;

    // ---- zero LDS ----
    for (int i = tid * 4; i < LDSB; i += NTH * 4) *(uint32_t*)(lds + i) = 0u;
    __syncthreads();

    // one-slots (bias column of B) in BOTH double buffers; x(t=0)
    if (tid < 32) {
        int db = tid >> 4, n = tid & 15;
        *(unsigned short*)(lds + vaddr(BASE0, RB0,  db, n,  54 * 2)) = 0x3C00; // f16 1.0
        *(unsigned short*)(lds + vaddr(BASE1, RB12, db, n, 112 * 2)) = 0x3C00;
        *(unsigned short*)(lds + vaddr(BASE2, RB12, db, n, 112 * 2)) = 0x3C00;
    } else if (tid >= 64 && tid < 96) {
        int i = tid - 64; int n = i & 15, f = i >> 4;
        const float* src = f ? g_time : g_input;
        float v = src[(size_t)(b0 + n) * Td];
        *(_Float16*)(lds + vaddr(BASE0, RB0, 0, n, (52 + f) * 2)) = (_Float16)v;
    }

    // ---- load weight A-fragments (f16, log2e-prescaled) ----
    // A-frag lane map (16x16x32): row = 16*tile + (lane&15), k = 32*s + 8*(lane>>4) + e
    // wave owns tiles {c, c+4, c+8, c+12}: gate gs rows = 64*gs + er, er = 16c + ncol
    const int er = 16 * c + ncol;
    const bool rvalid = (er < Hd);
    f16x8 AF[16];   // g0: [0..7] = 4 gates x 2 ksteps; g1/g2: [0..15] = 4 gates x 4 ksteps

    if (g == 0) {
        #pragma unroll
        for (int gs = 0; gs < 4; ++gs) {
            const int sr = gs * Hd + er;
            const float S = (gs == 2) ? LOG2E2 : LOG2E;   // g-gate: tanh(a)=2sig(2a)-1
            #pragma unroll
            for (int s = 0; s < 2; ++s)
                #pragma unroll
                for (int e = 0; e < 8; ++e) {
                    const int kk = 32 * s + 8 * kg + e;
                    float v = 0.f;
                    if (rvalid) {
                        if (kk < 51)                   v = Whh0[sr * 51 + kk];
                        else if (kk == 52 || kk == 53) v = Wih0[sr * 2 + (kk - 52)];
                        else if (kk == 54)             v = bih0[sr] + bhh0[sr];
                    }
                    AF[gs * 2 + s][e] = (_Float16)(v * S);
                }
        }
    } else {
        const float* Wih = (g == 1) ? Wih1 : Wih2;   // acts on prev-layer h (k 0..50)
        const float* Whh = (g == 1) ? Whh1 : Whh2;   // acts on own h (k 56..106)
        const float* bihp = (g == 1) ? bih1 : bih2;
        const float* bhhp = (g == 1) ? bhh1 : bhh2;
        #pragma unroll
        for (int gs = 0; gs < 4; ++gs) {
            const int sr = gs * Hd + er;
            const float S = (gs == 2) ? LOG2E2 : LOG2E;
            #pragma unroll
            for (int s = 0; s < 4; ++s)
                #pragma unroll
                for (int e = 0; e < 8; ++e) {
                    const int kk = 32 * s + 8 * kg + e;
                    float v = 0.f;
                    float sc = S;
                    if (rvalid) {
                        if (kk < 51)                   v = Wih[sr * 51 + kk];
                        else if (kk >= 56 && kk < 107) v = Whh[sr * 51 + (kk - 56)];
                        else if (kk == 112)            v = bihp[sr] + bhhp[sr];
                    } else if (g == 2 && gs == 0 && (er == 52 || er == 53)) {
                        const int hr = er - 52;        // head rows: LINEAR, unscaled
                        sc = 1.f;
                        if (kk >= 56 && kk < 107)      v = Wlin[hr * 51 + (kk - 56)];
                        else if (kk == 112)            v = blin[hr];
                    }
                    AF[gs * 4 + s][e] = (_Float16)(v * sc);
                }
        }
    }

    float cs[4];
    #pragma unroll
    for (int i = 0; i < 4; ++i) cs[i] = 0.f;

    const int e0 = 16 * c + 4 * kg;   // first element of this lane's 4 C rows
    const bool wr_ok = (e0 < Hd);     // guard: never touch x/one/pad slots
    const f32x4 Z = {0.f, 0.f, 0.f, 0.f};

    __syncthreads();

    // layer skew: iter n computes L0@t=n, L1@t=n-1, L2@t=n-2, head@t=n-3
    for (int n = 0; n <= Td + 2; ++n) {
        const int rb = n & 1, wb = rb ^ 1;

        if (g == 0) {  // ================= L0 group (+x prefetch on w0) ====
            const bool dopf = (w == 0 && lane < 32 && (n + 1) < Td);
            float pfv = 0.f;
            const int nb = lane & 15, f = (lane >> 4) & 1;
            if (dopf) {  // issue global load early; written to LDS below
                const float* src = f ? g_time : g_input;
                pfv = src[(size_t)(b0 + nb) * Td + (n + 1)];
            }
            if (n < Td) {
                f16x8 B0 = *(const f16x8*)(lds + vaddr(BASE0, RB0, rb, ncol, 16 * kg));
                f16x8 B1 = *(const f16x8*)(lds + vaddr(BASE0, RB0, rb, ncol, 64 + 16 * kg));
                f32x4 acc[4] = {Z, Z, Z, Z};
                __builtin_amdgcn_s_setprio(1);
                #pragma unroll
                for (int gs = 0; gs < 4; ++gs) {
                    acc[gs] = __builtin_amdgcn_mfma_f32_16x16x32_f16(AF[gs * 2 + 0], B0, acc[gs], 0, 0, 0);
                    acc[gs] = __builtin_amdgcn_mfma_f32_16x16x32_f16(AF[gs * 2 + 1], B1, acc[gs], 0, 0, 0);
                }
                __builtin_amdgcn_s_setprio(0);
                if (wr_ok)
                    update_write(lds, acc, cs,
                                 vaddr(BASE0, RB0,  wb, ncol, 2 * e0),
                                 vaddr(BASE1, RB12, wb, ncol, 2 * e0));
            }
            if (dopf)
                *(_Float16*)(lds + vaddr(BASE0, RB0, wb, nb, (52 + f) * 2)) = (_Float16)pfv;
        } else if (g == 1) {  // ============ L1 group =====================
            if (n >= 1 && n <= Td) {
                f16x8 Bh[4];
                #pragma unroll
                for (int s = 0; s < 4; ++s)
                    Bh[s] = *(const f16x8*)(lds + vaddr(BASE1, RB12, rb, ncol, 64 * s + 16 * kg));
                f32x4 acc[4] = {Z, Z, Z, Z};
                __builtin_amdgcn_s_setprio(1);
                #pragma unroll
                for (int s = 0; s < 4; ++s)
                    #pragma unroll
                    for (int gs = 0; gs < 4; ++gs)
                        acc[gs] = __builtin_amdgcn_mfma_f32_16x16x32_f16(AF[gs * 4 + s], Bh[s], acc[gs], 0, 0, 0);
                __builtin_amdgcn_s_setprio(0);
                if (wr_ok)
                    update_write(lds, acc, cs,
                                 vaddr(BASE1, RB12, wb, ncol, 112 + 2 * e0),
                                 vaddr(BASE2, RB12, wb, ncol, 2 * e0));
            }
        } else {  // ======================= L2 group (+head on w11) =======
            if (n >= 2) {
                f16x8 Bh[4];
                #pragma unroll
                for (int s = 0; s < 4; ++s)
                    Bh[s] = *(const f16x8*)(lds + vaddr(BASE2, RB12, rb, ncol, 64 * s + 16 * kg));
                f32x4 acc[4] = {Z, Z, Z, Z};
                __builtin_amdgcn_s_setprio(1);
                #pragma unroll
                for (int s = 0; s < 4; ++s)
                    #pragma unroll
                    for (int gs = 0; gs < 4; ++gs)
                        acc[gs] = __builtin_amdgcn_mfma_f32_16x16x32_f16(AF[gs * 4 + s], Bh[s], acc[gs], 0, 0, 0);
                __builtin_amdgcn_s_setprio(0);
                if (n <= Td + 1 && wr_ok)
                    update_write(lds, acc, cs,
                                 vaddr(BASE2, RB12, wb, ncol, 112 + 2 * e0), -1);
                if (w == 11 && kg == 1 && n >= 3) {
                    // head rows 52,53 -> tile c=3, within-tile rows 4,5 -> kg=1, regs 0,1
                    float mean = acc[0][0];
                    float spre = acc[0][1];
                    float sp = (spre > 30.f) ? spre : __logf(1.f + __expf(spre));
                    const int t = n - 3;
                    float2 o2 = make_float2(mean, sp);
                    *(float2*)&g_out[((size_t)(b0 + ncol) * Td + t) * 2] = o2;
                }
            }
        }
        __syncthreads();  // single barrier: wb writes become next iter's rb reads
    }
}

extern "C" void kernel_launch(void* const* d_in, const int* in_sizes, int n_in,
                              void* d_out, int out_size, void* d_ws, size_t ws_size,
                              hipStream_t stream) {
    const float* input = (const float*)d_in[0];
    const float* timei = (const float*)d_in[1];
    const float* Wih0  = (const float*)d_in[2];
    const float* Whh0  = (const float*)d_in[3];
    const float* bih0  = (const float*)d_in[4];
    const float* bhh0  = (const float*)d_in[5];
    const float* Wih1  = (const float*)d_in[6];
    const float* Whh1  = (const float*)d_in[7];
    const float* bih1  = (const float*)d_in[8];
    const float* bhh1  = (const float*)d_in[9];
    const float* Wih2  = (const float*)d_in[10];
    const float* Whh2  = (const float*)d_in[11];
    const float* bih2  = (const float*)d_in[12];
    const float* bhh2  = (const float*)d_in[13];
    const float* Wlin  = (const float*)d_in[14];
    const float* blin  = (const float*)d_in[15];
    float* out = (float*)d_out;

    lstm3_mfma<<<dim3(NBLK), dim3(NTH), 0, stream>>>(
        input, timei,
        Wih0, Whh0, bih0, bhh0,
        Wih1, Whh1, bih1, bhh1,
        Wih2, Whh2, bih2, bhh2,
        Wlin, blin, out);
}